// Round 5
// baseline (451.808 us; speedup 1.0000x reference)
//
#include <hip/hip_runtime.h>

typedef __attribute__((ext_vector_type(8))) short bfrag;
typedef __attribute__((ext_vector_type(4))) float f32x4;

__device__ __forceinline__ short f2bf(float f) {
  union { float f; unsigned u; } v; v.f = f;
  unsigned r = v.u + 0x7FFFu + ((v.u >> 16) & 1u);  // RNE
  return (short)(r >> 16);
}
__device__ __forceinline__ float bf2f(unsigned short h) {
  union { unsigned u; float f; } v; v.u = ((unsigned)h) << 16;
  return v.f;
}
__device__ __forceinline__ float gelu_exact(float g) {
  return 0.5f * g * (1.0f + erff(g * 0.70710678118654752f));
}
__device__ __forceinline__ void gld_lds16(const short* g, short* l) {
  __builtin_amdgcn_global_load_lds(
      (const __attribute__((address_space(1))) void*)g,
      (__attribute__((address_space(3))) void*)l, 16, 0, 0);
}

// ---------------- weights -> bf16 ----------------
// 8 float4/thread, ALL loads issued before any store; NT loads on read-once fp32.
__global__ __launch_bounds__(256) void k_convert_w(
    const float* __restrict__ s0, const float* __restrict__ s1,
    const float* __restrict__ s2, const float* __restrict__ s3,
    short* __restrict__ d0, short* __restrict__ d1,
    short* __restrict__ d2, short* __restrict__ d3)
{
  const int b = blockIdx.x;
  const float* s; short* d; long off;
  if (b < 3840)      { s = s0; d = d0; off = (long)b * 2048; }
  else if (b < 5760) { s = s1; d = d1; off = (long)(b - 3840) * 2048; }
  else if (b < 6272) { s = s2; d = d2; off = (long)(b - 5760) * 2048; }
  else               { s = s3; d = d3; off = (long)(b - 6272) * 2048; }
  const f32x4* sp = (const f32x4*)s;
  const long i0 = off + threadIdx.x;
  f32x4 v[8];
#pragma unroll
  for (int j = 0; j < 8; j++) v[j] = __builtin_nontemporal_load(sp + i0 + j * 256);
#pragma unroll
  for (int j = 0; j < 8; j++)
    ((short4*)d)[i0 + j * 256] =
        make_short4(f2bf(v[j].x), f2bf(v[j].y), f2bf(v[j].z), f2bf(v[j].w));
}

// ---------------- gating (4 tokens/wave) + x->bf16 fused ----------------
__global__ __launch_bounds__(64) void k_gate(const float* __restrict__ x,
    const float* __restrict__ gw, int* __restrict__ topk_idx,
    float* __restrict__ topk_w, short* __restrict__ xbf)
{
  const int t0 = blockIdx.x * 4;
  const int lane = threadIdx.x;
  float xv[4][16];
#pragma unroll
  for (int tt = 0; tt < 4; tt++)
#pragma unroll
    for (int i = 0; i < 16; i++) {
      xv[tt][i] = x[(size_t)(t0 + tt) * 1024 + lane + 64 * i];
      xbf[(size_t)(t0 + tt) * 1024 + lane + 64 * i] = f2bf(xv[tt][i]);
    }
  float p[4][15];
#pragma unroll
  for (int e = 0; e < 15; e++) {
    float wv[16];
#pragma unroll
    for (int i = 0; i < 16; i++) wv[i] = gw[(size_t)e * 1024 + lane + 64 * i];
#pragma unroll
    for (int tt = 0; tt < 4; tt++) {
      float s = 0.f;
#pragma unroll
      for (int i = 0; i < 16; i++) s += xv[tt][i] * wv[i];
#pragma unroll
      for (int o = 32; o; o >>= 1) s += __shfl_xor(s, o, 64);
      p[tt][e] = s;
    }
  }
#pragma unroll
  for (int tt = 0; tt < 4; tt++) {
    float m = -1e30f;
#pragma unroll
    for (int e = 0; e < 15; e++) m = fmaxf(m, p[tt][e]);
    float q[15], Z = 0.f;
#pragma unroll
    for (int e = 0; e < 15; e++) { q[e] = expf(p[tt][e] - m); Z += q[e]; }
    int usedMask = 0; int bi[3]; float bv[3];
#pragma unroll
    for (int j = 0; j < 3; j++) {
      float best = -1.f; int b = 0;
#pragma unroll
      for (int e = 0; e < 15; e++) {
        bool ok = (!((usedMask >> e) & 1)) && (q[e] > best);
        if (ok) { best = q[e]; b = e; }
      }
      bi[j] = b; bv[j] = best / Z; usedMask |= 1 << b;
    }
    if (lane == tt) {
      float den = bv[0] + bv[1] + bv[2] + 1e-20f;
#pragma unroll
      for (int j = 0; j < 3; j++) {
        topk_idx[(t0 + tt) * 3 + j] = bi[j];
        topk_w[(t0 + tt) * 3 + j] = bv[j] / den;
      }
    }
  }
}

// ---------------- routing: single block, LDS atomics ----------------
__global__ __launch_bounds__(1024) void k_route(const int* __restrict__ topk_idx,
    const float* __restrict__ topk_w, int* __restrict__ cnt_g, int* __restrict__ offs_g,
    int* __restrict__ row_tok, float* __restrict__ row_wt, int* __restrict__ row_id)
{
  __shared__ int scnt[16], soffs[16], sfill[16];
  const int tid = threadIdx.x;
  if (tid < 16) { scnt[tid] = 0; sfill[tid] = 0; }
  __syncthreads();
  for (int i = tid; i < 6144; i += 1024) atomicAdd(&scnt[topk_idx[i]], 1);
  __syncthreads();
  if (tid == 0) {
    int a = 0;
    for (int e = 0; e < 15; e++) { soffs[e] = a; offs_g[e] = a; cnt_g[e] = scnt[e]; a += scnt[e]; }
  }
  __syncthreads();
  for (int i = tid; i < 6144; i += 1024) {
    int e = topk_idx[i];
    int pos = atomicAdd(&sfill[e], 1);
    int row = soffs[e] + pos;
    row_tok[row] = i / 3;
    row_wt[row] = topk_w[i];
    row_id[i] = row;
  }
}

__device__ __forceinline__ bool resolve_tile128(const int* __restrict__ cnt, int ty,
                                                int& e, int& lt) {
  int acc = 0;
#pragma unroll
  for (int i = 0; i < 15; i++) {
    int tl = (cnt[i] + 127) >> 7;
    if (ty < acc + tl) { e = i; lt = ty - acc; return true; }
    acc += tl;
  }
  return false;
}

// ============== unified fc1 (+geglu): shared blocks [0,512), expert [512,1520) ==============
// 128(M) x 64(F) tile. Depth-3 pipelined staging: 4 LDS buffers (128 KB, 1 block/CU),
// ONE raw s_barrier per K-step, counted s_waitcnt vmcnt(16) instead of full drain.
// Loads stay in flight across 3 K-steps -> ~900cyc HBM latency fully covered.
// Race-freedom: stage into buf b (iter ks, after barrier) follows all waves' compute
// on b (iter ks-1, before their barrier arrival); compute on b (iter ks+3) follows
// each wave's own vmcnt retiring its b-loads + a barrier.
__global__ __launch_bounds__(256) void k_fc1(
    const short* __restrict__ xbf,
    const short* __restrict__ wsh, const float* __restrict__ bsh, const float* __restrict__ msh,
    const short* __restrict__ wex, const float* __restrict__ bex, const float* __restrict__ mex,
    const int* __restrict__ cnt, const int* __restrict__ offs, const int* __restrict__ row_tok,
    short* __restrict__ as_buf, short* __restrict__ a_buf)
{
  __shared__ short smem[4 * 16384];  // 128 KB: 4 x {A 16KB, B 16KB}
  const int tid = threadIdx.x;
  const int bid = blockIdx.x;
  const bool sh = bid < 512;
  int f0, m0 = 0, e = 0, rowBase = 0, nrows = 128;
  if (sh) {
    f0 = (bid & 31) * 64; m0 = (bid >> 5) * 128;
  } else {
    const int b2 = bid - 512;
    int lt;
    if (!resolve_tile128(cnt, b2 >> 4, e, lt)) return;
    f0 = (b2 & 15) * 64;
    rowBase = offs[e] + lt * 128;
    nrows = cnt[e] - lt * 128; if (nrows > 128) nrows = 128;
  }
  const int lane = tid & 63, ml = lane & 15, kq = lane >> 4, mlo = lane & 7;
  const int wv = tid >> 6, wr = wv >> 1, wc = wv & 1;
  const int lrow = lane >> 3, lchk = lane & 7;
  const int Fhalf = sh ? 2048 : 1024;
  const short* wptr = sh ? wsh : (wex + (size_t)e * 2048 * 1024);
  const short* aSrc[4]; const short* bSrc[4];
#pragma unroll
  for (int t = 0; t < 4; t++) {
    const int r = wv * 32 + t * 8 + lrow;
    const int sc = (lchk ^ (r & 7)) * 8;
    if (sh) aSrc[t] = xbf + (size_t)(m0 + r) * 1024 + sc;
    else {
      const int rc = r < nrows ? r : nrows - 1;
      aSrc[t] = xbf + (size_t)row_tok[rowBase + rc] * 1024 + sc;
    }
    const int grow = (r < 64) ? (f0 + r) : (Fhalf + f0 + r - 64);
    bSrc[t] = wptr + (size_t)grow * 1024 + sc;
  }
  f32x4 acc[4][4] = {};

#define FC1_STAGE(BUF, K0) do {                                              \
    short* A_ = smem + (BUF) * 16384;                                        \
    short* B_ = A_ + 8192;                                                   \
    _Pragma("unroll")                                                        \
    for (int t = 0; t < 4; t++) gld_lds16(aSrc[t] + (K0), A_ + (wv * 32 + t * 8) * 64); \
    _Pragma("unroll")                                                        \
    for (int t = 0; t < 4; t++) gld_lds16(bSrc[t] + (K0), B_ + (wv * 32 + t * 8) * 64); \
  } while (0)

#define FC1_COMPUTE(BUF) do {                                                \
    const short* As_ = smem + (BUF) * 16384;                                 \
    const short* Bs_ = As_ + 8192;                                           \
    _Pragma("unroll")                                                        \
    for (int kk = 0; kk < 2; kk++) {                                         \
      const int so = ((kk * 4 + kq) ^ mlo) * 8;                              \
      bfrag af[4], bb[4];                                                    \
      _Pragma("unroll")                                                      \
      for (int i = 0; i < 4; i++)                                            \
        af[i] = *(const bfrag*)&As_[(wr * 64 + i * 16 + ml) * 64 + so];      \
      _Pragma("unroll")                                                      \
      for (int j = 0; j < 4; j++) {                                          \
        const int brow = ((j >> 1) ? 64 : 0) + wc * 32 + (j & 1) * 16 + ml;  \
        bb[j] = *(const bfrag*)&Bs_[brow * 64 + so];                         \
      }                                                                      \
      _Pragma("unroll")                                                      \
      for (int i = 0; i < 4; i++)                                            \
        _Pragma("unroll")                                                    \
        for (int j = 0; j < 4; j++)                                          \
          acc[i][j] = __builtin_amdgcn_mfma_f32_16x16x32_bf16(af[i], bb[j], acc[i][j], 0, 0, 0); \
    }                                                                        \
  } while (0)

  FC1_STAGE(0, 0);
  FC1_STAGE(1, 64);
  FC1_STAGE(2, 128);
#pragma unroll 4
  for (int ks = 0; ks < 16; ks++) {
    if (ks < 14)       asm volatile("s_waitcnt vmcnt(16)" ::: "memory");
    else if (ks == 14) asm volatile("s_waitcnt vmcnt(8)" ::: "memory");
    else               asm volatile("s_waitcnt vmcnt(0)" ::: "memory");
    __builtin_amdgcn_s_barrier();
    __builtin_amdgcn_sched_barrier(0);
    if (ks + 3 < 16) FC1_STAGE((ks + 3) & 3, (ks + 3) * 64);
    FC1_COMPUTE(ks & 3);
  }

  // in-register geglu epilogue: 32 outputs/lane, all 4 waves participate
  const float* bias = sh ? bsh : (bex + (size_t)e * 2048);
  const float* mult = sh ? msh : (mex + (size_t)e * 1024);
#pragma unroll
  for (int jj = 0; jj < 2; jj++) {
    const int fl = wc * 32 + jj * 16 + ml;
    const int f = f0 + fl;
    const float b1 = bias[f];
    const float b2 = bias[Fhalf + f];
    const float mv = mult[f];
#pragma unroll
    for (int i = 0; i < 4; i++)
#pragma unroll
      for (int rg = 0; rg < 4; rg++) {
        const int row = wr * 64 + i * 16 + kq * 4 + rg;
        const float h1 = acc[i][jj][rg] + b1;
        const float h2 = acc[i][jj + 2][rg] + b2;
        const short o = f2bf(gelu_exact(h2) * h1 * mv);
        if (sh) as_buf[(size_t)(m0 + row) * 2048 + f] = o;
        else if (row < nrows) a_buf[(size_t)(rowBase + row) * 1024 + f] = o;
      }
  }
}

// ============== unified fc2: shared blocks [0,128), expert [128,632) ==============
// 128(M) x 128(D) tile; same depth-3 counted-vmcnt pipeline as fc1.
__global__ __launch_bounds__(256) void k_fc2(
    const short* __restrict__ as_buf, const short* __restrict__ wsfc2, const float* __restrict__ s_b,
    const short* __restrict__ a_buf, const short* __restrict__ wfc2, const float* __restrict__ e_b,
    const int* __restrict__ cnt, const int* __restrict__ offs, const float* __restrict__ row_wt,
    float* __restrict__ y, short* __restrict__ yexp)
{
  __shared__ short smem[4 * 16384];  // 128 KB
  const int tid = threadIdx.x;
  const int bid = blockIdx.x;
  const bool sh = bid < 128;
  int d0, m0 = 0, e = 0, rowBase = 0, nrows = 128, Klen, astr, bstr;
  const short *aBase, *bBase;
  if (sh) {
    d0 = (bid & 7) * 128; m0 = (bid >> 3) * 128;
    Klen = 2048; astr = 2048; bstr = 2048;
    aBase = as_buf; bBase = wsfc2;
  } else {
    const int b2 = bid - 128;
    int lt;
    if (!resolve_tile128(cnt, b2 >> 3, e, lt)) return;
    d0 = (b2 & 7) * 128;
    rowBase = offs[e] + lt * 128;
    nrows = cnt[e] - lt * 128; if (nrows > 128) nrows = 128;
    Klen = 1024; astr = 1024; bstr = 1024;
    aBase = a_buf + (size_t)rowBase * 1024;
    bBase = wfc2 + (size_t)e * 1024 * 1024;
  }
  const int lane = tid & 63, ml = lane & 15, kq = lane >> 4, mlo = lane & 7;
  const int wv = tid >> 6, wr = wv >> 1, wc = wv & 1;
  const int lrow = lane >> 3, lchk = lane & 7;
  const short* aSrc[4]; const short* bSrc[4];
#pragma unroll
  for (int t = 0; t < 4; t++) {
    const int r = wv * 32 + t * 8 + lrow;
    const int sc = (lchk ^ (r & 7)) * 8;
    aSrc[t] = aBase + (size_t)(sh ? (m0 + r) : r) * astr + sc;
    bSrc[t] = bBase + (size_t)(d0 + r) * bstr + sc;
  }
  f32x4 acc[4][4] = {};

#define FC2_STAGE(BUF, K0) do {                                              \
    short* A_ = smem + (BUF) * 16384;                                        \
    short* B_ = A_ + 8192;                                                   \
    _Pragma("unroll")                                                        \
    for (int t = 0; t < 4; t++) gld_lds16(aSrc[t] + (K0), A_ + (wv * 32 + t * 8) * 64); \
    _Pragma("unroll")                                                        \
    for (int t = 0; t < 4; t++) gld_lds16(bSrc[t] + (K0), B_ + (wv * 32 + t * 8) * 64); \
  } while (0)

#define FC2_COMPUTE(BUF) do {                                                \
    const short* As_ = smem + (BUF) * 16384;                                 \
    const short* Bs_ = As_ + 8192;                                           \
    _Pragma("unroll")                                                        \
    for (int kk = 0; kk < 2; kk++) {                                         \
      const int so = ((kk * 4 + kq) ^ mlo) * 8;                              \
      bfrag af[4], bb[4];                                                    \
      _Pragma("unroll")                                                      \
      for (int i = 0; i < 4; i++)                                            \
        af[i] = *(const bfrag*)&As_[(wr * 64 + i * 16 + ml) * 64 + so];      \
      _Pragma("unroll")                                                      \
      for (int j = 0; j < 4; j++)                                            \
        bb[j] = *(const bfrag*)&Bs_[(wc * 64 + j * 16 + ml) * 64 + so];      \
      _Pragma("unroll")                                                      \
      for (int i = 0; i < 4; i++)                                            \
        _Pragma("unroll")                                                    \
        for (int j = 0; j < 4; j++)                                          \
          acc[i][j] = __builtin_amdgcn_mfma_f32_16x16x32_bf16(af[i], bb[j], acc[i][j], 0, 0, 0); \
    }                                                                        \
  } while (0)

  FC2_STAGE(0, 0);
  FC2_STAGE(1, 64);
  FC2_STAGE(2, 128);
  const int NK = Klen >> 6;
  for (int ks = 0; ks < NK; ks++) {
    if (ks + 2 < NK)      asm volatile("s_waitcnt vmcnt(16)" ::: "memory");
    else if (ks + 1 < NK) asm volatile("s_waitcnt vmcnt(8)" ::: "memory");
    else                  asm volatile("s_waitcnt vmcnt(0)" ::: "memory");
    __builtin_amdgcn_s_barrier();
    __builtin_amdgcn_sched_barrier(0);
    if (ks + 3 < NK) FC2_STAGE((ks + 3) & 3, (ks + 3) * 64);
    FC2_COMPUTE(ks & 3);
  }

#pragma unroll
  for (int j = 0; j < 4; j++) {
    const int d = d0 + wc * 64 + j * 16 + ml;
    const float bv = sh ? s_b[d] : e_b[(size_t)e * 1024 + d];
#pragma unroll
    for (int i = 0; i < 4; i++)
#pragma unroll
      for (int rg = 0; rg < 4; rg++) {
        const int row = wr * 64 + i * 16 + kq * 4 + rg;
        if (sh) {
          y[(size_t)(m0 + row) * 1024 + d] = acc[i][j][rg] + bv;
        } else if (row < nrows) {
          const float wt = row_wt[rowBase + row];
          yexp[(size_t)(rowBase + row) * 1024 + d] = f2bf((acc[i][j][rg] + bv) * wt);
        }
      }
  }
}

// ---------------- combine ----------------
__global__ __launch_bounds__(256) void k_combine(float* __restrict__ y,
    const short* __restrict__ yexp, const int* __restrict__ row_id)
{
  const int idx = blockIdx.x * 256 + threadIdx.x;
  const int t = idx >> 8;
  const int d4 = (idx & 255) * 4;
  const int r0 = row_id[t * 3], r1 = row_id[t * 3 + 1], r2 = row_id[t * 3 + 2];
  float4 acc = *(float4*)(y + (size_t)t * 1024 + d4);
  const ushort4 v0 = *(const ushort4*)(yexp + (size_t)r0 * 1024 + d4);
  const ushort4 v1 = *(const ushort4*)(yexp + (size_t)r1 * 1024 + d4);
  const ushort4 v2 = *(const ushort4*)(yexp + (size_t)r2 * 1024 + d4);
  acc.x += bf2f(v0.x) + bf2f(v1.x) + bf2f(v2.x);
  acc.y += bf2f(v0.y) + bf2f(v1.y) + bf2f(v2.y);
  acc.z += bf2f(v0.z) + bf2f(v1.z) + bf2f(v2.z);
  acc.w += bf2f(v0.w) + bf2f(v1.w) + bf2f(v2.w);
  *(float4*)(y + (size_t)t * 1024 + d4) = acc;
}

extern "C" void kernel_launch(void* const* d_in, const int* in_sizes, int n_in,
                              void* d_out, int out_size, void* d_ws, size_t ws_size,
                              hipStream_t stream) {
  const float* x          = (const float*)d_in[0];
  const float* gate_w     = (const float*)d_in[1];
  const float* fc1_w      = (const float*)d_in[2];
  const float* fc1_b      = (const float*)d_in[3];
  const float* geglu_mult = (const float*)d_in[4];
  const float* fc2_w      = (const float*)d_in[5];
  const float* fc2_b      = (const float*)d_in[6];
  const float* s_fc1_w    = (const float*)d_in[7];
  const float* s_fc1_b    = (const float*)d_in[8];
  const float* s_mult     = (const float*)d_in[9];
  const float* s_fc2_w    = (const float*)d_in[10];
  const float* s_fc2_b    = (const float*)d_in[11];
  float* y = (float*)d_out;

  char* wsb = (char*)d_ws;
  int*   cnt      = (int*)(wsb + 0);
  int*   offs     = (int*)(wsb + 64);
  int*   topk_idx = (int*)(wsb + 256);
  float* topk_w   = (float*)(wsb + 24832);
  int*   row_tok  = (int*)(wsb + 49408);
  float* row_wt   = (float*)(wsb + 74496);
  int*   row_id   = (int*)(wsb + 99584);
  short* xbf      = (short*)(wsb + 131072);       // 2048x1024
  short* a_buf    = (short*)(wsb + 8519680);      // 6272x1024
  short* as_buf   = (short*)(wsb + 21364736);     // 2048x2048
  short* yexp     = (short*)(wsb + 29753344);     // 6272x1024
  short* wbf_sfc1 = (short*)(wsb + 42598400);     // 4096x1024
  short* wbf_sfc2 = (short*)(wsb + 50987008);     // 1024x2048
  short* wbf_fc1  = (short*)(wsb + 55181312);     // 15x2048x1024
  short* wbf_fc2  = (short*)(wsb + 118095872);    // 15x1024x1024
  // total ~149.6 MB

  k_convert_w<<<6528, 256, 0, stream>>>(fc1_w, fc2_w, s_fc1_w, s_fc2_w,
                                        wbf_fc1, wbf_fc2, wbf_sfc1, wbf_sfc2);
  k_gate<<<512, 64, 0, stream>>>(x, gate_w, topk_idx, topk_w, xbf);
  k_route<<<1, 1024, 0, stream>>>(topk_idx, topk_w, cnt, offs, row_tok, row_wt, row_id);
  k_fc1<<<1520, 256, 0, stream>>>(xbf, wbf_sfc1, s_fc1_b, s_mult,
                                  wbf_fc1, fc1_b, geglu_mult,
                                  cnt, offs, row_tok, as_buf, a_buf);
  k_fc2<<<632, 256, 0, stream>>>(as_buf, wbf_sfc2, s_fc2_b,
                                 a_buf, wbf_fc2, fc2_b,
                                 cnt, offs, row_wt, y, yexp);
  k_combine<<<2048, 256, 0, stream>>>(y, yexp, row_id);
}

// Round 6
// 415.797 us; speedup vs baseline: 1.0866x; 1.0866x over previous
//
#include <hip/hip_runtime.h>

typedef __attribute__((ext_vector_type(8))) short bfrag;
typedef __attribute__((ext_vector_type(4))) float f32x4;

__device__ __forceinline__ short f2bf(float f) {
  union { float f; unsigned u; } v; v.f = f;
  unsigned r = v.u + 0x7FFFu + ((v.u >> 16) & 1u);  // RNE
  return (short)(r >> 16);
}
__device__ __forceinline__ float bf2f(unsigned short h) {
  union { unsigned u; float f; } v; v.u = ((unsigned)h) << 16;
  return v.f;
}
__device__ __forceinline__ float gelu_exact(float g) {
  return 0.5f * g * (1.0f + erff(g * 0.70710678118654752f));
}
__device__ __forceinline__ void gld_lds16(const short* g, short* l) {
  __builtin_amdgcn_global_load_lds(
      (const __attribute__((address_space(1))) void*)g,
      (__attribute__((address_space(3))) void*)l, 16, 0, 0);
}

// ---------------- weights -> bf16 ----------------
// 8 float4/thread, ALL loads issued before any store; NT loads on read-once fp32.
__global__ __launch_bounds__(256) void k_convert_w(
    const float* __restrict__ s0, const float* __restrict__ s1,
    const float* __restrict__ s2, const float* __restrict__ s3,
    short* __restrict__ d0, short* __restrict__ d1,
    short* __restrict__ d2, short* __restrict__ d3)
{
  const int b = blockIdx.x;
  const float* s; short* d; long off;
  if (b < 3840)      { s = s0; d = d0; off = (long)b * 2048; }
  else if (b < 5760) { s = s1; d = d1; off = (long)(b - 3840) * 2048; }
  else if (b < 6272) { s = s2; d = d2; off = (long)(b - 5760) * 2048; }
  else               { s = s3; d = d3; off = (long)(b - 6272) * 2048; }
  const f32x4* sp = (const f32x4*)s;
  const long i0 = off + threadIdx.x;
  f32x4 v[8];
#pragma unroll
  for (int j = 0; j < 8; j++) v[j] = __builtin_nontemporal_load(sp + i0 + j * 256);
#pragma unroll
  for (int j = 0; j < 8; j++)
    ((short4*)d)[i0 + j * 256] =
        make_short4(f2bf(v[j].x), f2bf(v[j].y), f2bf(v[j].z), f2bf(v[j].w));
}

// ---------------- gating (4 tokens/wave) + x->bf16 fused ----------------
__global__ __launch_bounds__(64) void k_gate(const float* __restrict__ x,
    const float* __restrict__ gw, int* __restrict__ topk_idx,
    float* __restrict__ topk_w, short* __restrict__ xbf)
{
  const int t0 = blockIdx.x * 4;
  const int lane = threadIdx.x;
  float xv[4][16];
#pragma unroll
  for (int tt = 0; tt < 4; tt++)
#pragma unroll
    for (int i = 0; i < 16; i++) {
      xv[tt][i] = x[(size_t)(t0 + tt) * 1024 + lane + 64 * i];
      xbf[(size_t)(t0 + tt) * 1024 + lane + 64 * i] = f2bf(xv[tt][i]);
    }
  float p[4][15];
#pragma unroll
  for (int e = 0; e < 15; e++) {
    float wv[16];
#pragma unroll
    for (int i = 0; i < 16; i++) wv[i] = gw[(size_t)e * 1024 + lane + 64 * i];
#pragma unroll
    for (int tt = 0; tt < 4; tt++) {
      float s = 0.f;
#pragma unroll
      for (int i = 0; i < 16; i++) s += xv[tt][i] * wv[i];
#pragma unroll
      for (int o = 32; o; o >>= 1) s += __shfl_xor(s, o, 64);
      p[tt][e] = s;
    }
  }
#pragma unroll
  for (int tt = 0; tt < 4; tt++) {
    float m = -1e30f;
#pragma unroll
    for (int e = 0; e < 15; e++) m = fmaxf(m, p[tt][e]);
    float q[15], Z = 0.f;
#pragma unroll
    for (int e = 0; e < 15; e++) { q[e] = expf(p[tt][e] - m); Z += q[e]; }
    int usedMask = 0; int bi[3]; float bv[3];
#pragma unroll
    for (int j = 0; j < 3; j++) {
      float best = -1.f; int b = 0;
#pragma unroll
      for (int e = 0; e < 15; e++) {
        bool ok = (!((usedMask >> e) & 1)) && (q[e] > best);
        if (ok) { best = q[e]; b = e; }
      }
      bi[j] = b; bv[j] = best / Z; usedMask |= 1 << b;
    }
    if (lane == tt) {
      float den = bv[0] + bv[1] + bv[2] + 1e-20f;
#pragma unroll
      for (int j = 0; j < 3; j++) {
        topk_idx[(t0 + tt) * 3 + j] = bi[j];
        topk_w[(t0 + tt) * 3 + j] = bv[j] / den;
      }
    }
  }
}

// ---------------- routing: single block, LDS atomics ----------------
__global__ __launch_bounds__(1024) void k_route(const int* __restrict__ topk_idx,
    const float* __restrict__ topk_w, int* __restrict__ cnt_g, int* __restrict__ offs_g,
    int* __restrict__ row_tok, float* __restrict__ row_wt, int* __restrict__ row_id)
{
  __shared__ int scnt[16], soffs[16], sfill[16];
  const int tid = threadIdx.x;
  if (tid < 16) { scnt[tid] = 0; sfill[tid] = 0; }
  __syncthreads();
  for (int i = tid; i < 6144; i += 1024) atomicAdd(&scnt[topk_idx[i]], 1);
  __syncthreads();
  if (tid == 0) {
    int a = 0;
    for (int e = 0; e < 15; e++) { soffs[e] = a; offs_g[e] = a; cnt_g[e] = scnt[e]; a += scnt[e]; }
  }
  __syncthreads();
  for (int i = tid; i < 6144; i += 1024) {
    int e = topk_idx[i];
    int pos = atomicAdd(&sfill[e], 1);
    int row = soffs[e] + pos;
    row_tok[row] = i / 3;
    row_wt[row] = topk_w[i];
    row_id[i] = row;
  }
}

__device__ __forceinline__ bool resolve_tile256(const int* __restrict__ cnt, int ty,
                                                int& e, int& lt) {
  int acc = 0;
#pragma unroll
  for (int i = 0; i < 15; i++) {
    int tl = (cnt[i] + 255) >> 8;
    if (ty < acc + tl) { e = i; lt = ty - acc; return true; }
    acc += tl;
  }
  return false;
}

// ============== unified fc1 (+geglu): shared blocks [0,128), expert [128,440) ==============
// 256(M) x 128(F) tile, 8 waves (2 M-halves x 4 f-quarters). B-tile 256 rows
// (0-127 h1, 128-255 h2, same f-columns). Halves staged-bytes/FLOP vs 128x64:
// the measured limiter is staging throughput (~7.5 TB/s blended), not latency.
// 2-phase double buffer, 1 barrier-pair per K-step. LDS 128 KB -> 1 block/CU,
// 8 waves = 2 waves/SIMD (same as old 2-block config).
__global__ __launch_bounds__(512, 2) void k_fc1(
    const short* __restrict__ xbf,
    const short* __restrict__ wsh, const float* __restrict__ bsh, const float* __restrict__ msh,
    const short* __restrict__ wex, const float* __restrict__ bex, const float* __restrict__ mex,
    const int* __restrict__ cnt, const int* __restrict__ offs, const int* __restrict__ row_tok,
    short* __restrict__ as_buf, short* __restrict__ a_buf)
{
  __shared__ short smem[2 * 32768];  // 128 KB: 2 x {A 32KB, B 32KB}
  const int tid = threadIdx.x;
  const int bid = blockIdx.x;
  const bool sh = bid < 128;
  int f0, m0 = 0, e = 0, rowBase = 0, nrows = 256;
  if (sh) {
    f0 = (bid & 15) * 128; m0 = (bid >> 4) * 256;
  } else {
    const int b2 = bid - 128;
    int lt;
    if (!resolve_tile256(cnt, b2 >> 3, e, lt)) return;
    f0 = (b2 & 7) * 128;
    rowBase = offs[e] + lt * 256;
    nrows = cnt[e] - lt * 256; if (nrows > 256) nrows = 256;
  }
  const int lane = tid & 63, ml = lane & 15, kq = lane >> 4, mlo = lane & 7;
  const int wv = tid >> 6, wr = wv >> 2, wc = wv & 3;
  const int lrow = lane >> 3, lchk = lane & 7;
  const int Fhalf = sh ? 2048 : 1024;
  const short* wptr = sh ? wsh : (wex + (size_t)e * 2048 * 1024);
  const short* aSrc[4]; const short* bSrc[4];
#pragma unroll
  for (int t = 0; t < 4; t++) {
    const int r = wv * 32 + t * 8 + lrow;          // 0..255
    const int sc = (lchk ^ (r & 7)) * 8;
    if (sh) aSrc[t] = xbf + (size_t)(m0 + r) * 1024 + sc;
    else {
      const int rc = r < nrows ? r : nrows - 1;
      aSrc[t] = xbf + (size_t)row_tok[rowBase + rc] * 1024 + sc;
    }
    const int grow = (r < 128) ? (f0 + r) : (Fhalf + f0 + r - 128);
    bSrc[t] = wptr + (size_t)grow * 1024 + sc;
  }
  f32x4 acc[8][4] = {};

#define FC1_STAGE(BUF, K0) do {                                              \
    short* A_ = smem + (BUF) * 32768;                                        \
    short* B_ = A_ + 16384;                                                  \
    _Pragma("unroll")                                                        \
    for (int t = 0; t < 4; t++) gld_lds16(aSrc[t] + (K0), A_ + (wv * 32 + t * 8) * 64); \
    _Pragma("unroll")                                                        \
    for (int t = 0; t < 4; t++) gld_lds16(bSrc[t] + (K0), B_ + (wv * 32 + t * 8) * 64); \
  } while (0)

#define FC1_COMPUTE(BUF) do {                                                \
    const short* As_ = smem + (BUF) * 32768;                                 \
    const short* Bs_ = As_ + 16384;                                          \
    _Pragma("unroll")                                                        \
    for (int kk = 0; kk < 2; kk++) {                                         \
      const int so = ((kk * 4 + kq) ^ mlo) * 8;                              \
      bfrag af[8], bb[4];                                                    \
      _Pragma("unroll")                                                      \
      for (int i = 0; i < 8; i++)                                            \
        af[i] = *(const bfrag*)&As_[(wr * 128 + i * 16 + ml) * 64 + so];     \
      _Pragma("unroll")                                                      \
      for (int j = 0; j < 4; j++) {                                          \
        const int brow = (j >> 1) * 128 + wc * 32 + (j & 1) * 16 + ml;       \
        bb[j] = *(const bfrag*)&Bs_[brow * 64 + so];                         \
      }                                                                      \
      _Pragma("unroll")                                                      \
      for (int i = 0; i < 8; i++)                                            \
        _Pragma("unroll")                                                    \
        for (int j = 0; j < 4; j++)                                          \
          acc[i][j] = __builtin_amdgcn_mfma_f32_16x16x32_bf16(af[i], bb[j], acc[i][j], 0, 0, 0); \
    }                                                                        \
  } while (0)

  FC1_STAGE(0, 0);
  __syncthreads();
  int cur = 0;
  for (int ks = 0; ks < 15; ks++) {
    FC1_STAGE(cur ^ 1, (ks + 1) * 64);  // prefetch next tile (overlaps compute)
    FC1_COMPUTE(cur);
    __syncthreads();                     // drains vmcnt: next buffer ready
    cur ^= 1;
  }
  FC1_COMPUTE(cur);

  // in-register geglu epilogue: 64 outputs/lane
  const float* bias = sh ? bsh : (bex + (size_t)e * 2048);
  const float* mult = sh ? msh : (mex + (size_t)e * 1024);
#pragma unroll
  for (int jj = 0; jj < 2; jj++) {
    const int fl = wc * 32 + jj * 16 + ml;
    const int f = f0 + fl;
    const float b1 = bias[f];
    const float b2 = bias[Fhalf + f];
    const float mv = mult[f];
#pragma unroll
    for (int i = 0; i < 8; i++)
#pragma unroll
      for (int rg = 0; rg < 4; rg++) {
        const int row = wr * 128 + i * 16 + kq * 4 + rg;
        const float h1 = acc[i][jj][rg] + b1;
        const float h2 = acc[i][jj + 2][rg] + b2;
        const short o = f2bf(gelu_exact(h2) * h1 * mv);
        if (sh) as_buf[(size_t)(m0 + row) * 2048 + f] = o;
        else if (row < nrows) a_buf[(size_t)(rowBase + row) * 1024 + f] = o;
      }
  }
}

// ============== unified fc2: shared blocks [0,64), expert [64,376) ==============
// 256(M) x 128(D) tile, 8 waves (2 M-halves x 4 d-quarters); same staging scheme.
__global__ __launch_bounds__(512, 2) void k_fc2(
    const short* __restrict__ as_buf, const short* __restrict__ wsfc2, const float* __restrict__ s_b,
    const short* __restrict__ a_buf, const short* __restrict__ wfc2, const float* __restrict__ e_b,
    const int* __restrict__ cnt, const int* __restrict__ offs, const float* __restrict__ row_wt,
    float* __restrict__ y, short* __restrict__ yexp)
{
  __shared__ short smem[2 * 24576];  // 96 KB: 2 x {A 32KB, B 16KB}
  const int tid = threadIdx.x;
  const int bid = blockIdx.x;
  const bool sh = bid < 64;
  int d0, m0 = 0, e = 0, rowBase = 0, nrows = 256, Klen, astr, bstr;
  const short *aBase, *bBase;
  if (sh) {
    d0 = (bid & 7) * 128; m0 = (bid >> 3) * 256;
    Klen = 2048; astr = 2048; bstr = 2048;
    aBase = as_buf; bBase = wsfc2;
  } else {
    const int b2 = bid - 64;
    int lt;
    if (!resolve_tile256(cnt, b2 >> 3, e, lt)) return;
    d0 = (b2 & 7) * 128;
    rowBase = offs[e] + lt * 256;
    nrows = cnt[e] - lt * 256; if (nrows > 256) nrows = 256;
    Klen = 1024; astr = 1024; bstr = 1024;
    aBase = a_buf + (size_t)rowBase * 1024;
    bBase = wfc2 + (size_t)e * 1024 * 1024;
  }
  const int lane = tid & 63, ml = lane & 15, kq = lane >> 4, mlo = lane & 7;
  const int wv = tid >> 6, wr = wv >> 2, wc = wv & 3;
  const int lrow = lane >> 3, lchk = lane & 7;
  const short* aSrc[4]; const short* bSrc[2];
#pragma unroll
  for (int t = 0; t < 4; t++) {
    const int r = wv * 32 + t * 8 + lrow;          // 0..255
    const int sc = (lchk ^ (r & 7)) * 8;
    const int rc = (sh || r < nrows) ? r : nrows - 1;
    aSrc[t] = aBase + (size_t)(sh ? (m0 + r) : rc) * astr + sc;
  }
#pragma unroll
  for (int t = 0; t < 2; t++) {
    const int rb = wv * 16 + t * 8 + lrow;         // 0..127
    const int sc = (lchk ^ (rb & 7)) * 8;
    bSrc[t] = bBase + (size_t)(d0 + rb) * bstr + sc;
  }
  f32x4 acc[8][2] = {};

#define FC2_STAGE(BUF, K0) do {                                              \
    short* A_ = smem + (BUF) * 24576;                                        \
    short* B_ = A_ + 16384;                                                  \
    _Pragma("unroll")                                                        \
    for (int t = 0; t < 4; t++) gld_lds16(aSrc[t] + (K0), A_ + (wv * 32 + t * 8) * 64); \
    _Pragma("unroll")                                                        \
    for (int t = 0; t < 2; t++) gld_lds16(bSrc[t] + (K0), B_ + (wv * 16 + t * 8) * 64); \
  } while (0)

#define FC2_COMPUTE(BUF) do {                                                \
    const short* As_ = smem + (BUF) * 24576;                                 \
    const short* Bs_ = As_ + 16384;                                          \
    _Pragma("unroll")                                                        \
    for (int kk = 0; kk < 2; kk++) {                                         \
      const int so = ((kk * 4 + kq) ^ mlo) * 8;                              \
      bfrag af[8], bb[2];                                                    \
      _Pragma("unroll")                                                      \
      for (int i = 0; i < 8; i++)                                            \
        af[i] = *(const bfrag*)&As_[(wr * 128 + i * 16 + ml) * 64 + so];     \
      _Pragma("unroll")                                                      \
      for (int j = 0; j < 2; j++)                                            \
        bb[j] = *(const bfrag*)&Bs_[(wc * 32 + j * 16 + ml) * 64 + so];      \
      _Pragma("unroll")                                                      \
      for (int i = 0; i < 8; i++)                                            \
        _Pragma("unroll")                                                    \
        for (int j = 0; j < 2; j++)                                          \
          acc[i][j] = __builtin_amdgcn_mfma_f32_16x16x32_bf16(af[i], bb[j], acc[i][j], 0, 0, 0); \
    }                                                                        \
  } while (0)

  FC2_STAGE(0, 0);
  __syncthreads();
  int cur = 0;
  const int NK = Klen >> 6;
  for (int ks = 0; ks < NK - 1; ks++) {
    FC2_STAGE(cur ^ 1, (ks + 1) * 64);
    FC2_COMPUTE(cur);
    __syncthreads();
    cur ^= 1;
  }
  FC2_COMPUTE(cur);

#pragma unroll
  for (int j = 0; j < 2; j++) {
    const int d = d0 + wc * 32 + j * 16 + ml;
    const float bv = sh ? s_b[d] : e_b[(size_t)e * 1024 + d];
#pragma unroll
    for (int i = 0; i < 8; i++)
#pragma unroll
      for (int rg = 0; rg < 4; rg++) {
        const int row = wr * 128 + i * 16 + kq * 4 + rg;
        if (sh) {
          y[(size_t)(m0 + row) * 1024 + d] = acc[i][j][rg] + bv;
        } else if (row < nrows) {
          const float wt = row_wt[rowBase + row];
          yexp[(size_t)(rowBase + row) * 1024 + d] = f2bf((acc[i][j][rg] + bv) * wt);
        }
      }
  }
}

// ---------------- combine ----------------
__global__ __launch_bounds__(256) void k_combine(float* __restrict__ y,
    const short* __restrict__ yexp, const int* __restrict__ row_id)
{
  const int idx = blockIdx.x * 256 + threadIdx.x;
  const int t = idx >> 8;
  const int d4 = (idx & 255) * 4;
  const int r0 = row_id[t * 3], r1 = row_id[t * 3 + 1], r2 = row_id[t * 3 + 2];
  float4 acc = *(float4*)(y + (size_t)t * 1024 + d4);
  const ushort4 v0 = *(const ushort4*)(yexp + (size_t)r0 * 1024 + d4);
  const ushort4 v1 = *(const ushort4*)(yexp + (size_t)r1 * 1024 + d4);
  const ushort4 v2 = *(const ushort4*)(yexp + (size_t)r2 * 1024 + d4);
  acc.x += bf2f(v0.x) + bf2f(v1.x) + bf2f(v2.x);
  acc.y += bf2f(v0.y) + bf2f(v1.y) + bf2f(v2.y);
  acc.z += bf2f(v0.z) + bf2f(v1.z) + bf2f(v2.z);
  acc.w += bf2f(v0.w) + bf2f(v1.w) + bf2f(v2.w);
  *(float4*)(y + (size_t)t * 1024 + d4) = acc;
}

extern "C" void kernel_launch(void* const* d_in, const int* in_sizes, int n_in,
                              void* d_out, int out_size, void* d_ws, size_t ws_size,
                              hipStream_t stream) {
  const float* x          = (const float*)d_in[0];
  const float* gate_w     = (const float*)d_in[1];
  const float* fc1_w      = (const float*)d_in[2];
  const float* fc1_b      = (const float*)d_in[3];
  const float* geglu_mult = (const float*)d_in[4];
  const float* fc2_w      = (const float*)d_in[5];
  const float* fc2_b      = (const float*)d_in[6];
  const float* s_fc1_w    = (const float*)d_in[7];
  const float* s_fc1_b    = (const float*)d_in[8];
  const float* s_mult     = (const float*)d_in[9];
  const float* s_fc2_w    = (const float*)d_in[10];
  const float* s_fc2_b    = (const float*)d_in[11];
  float* y = (float*)d_out;

  char* wsb = (char*)d_ws;
  int*   cnt      = (int*)(wsb + 0);
  int*   offs     = (int*)(wsb + 64);
  int*   topk_idx = (int*)(wsb + 256);
  float* topk_w   = (float*)(wsb + 24832);
  int*   row_tok  = (int*)(wsb + 49408);
  float* row_wt   = (float*)(wsb + 74496);
  int*   row_id   = (int*)(wsb + 99584);
  short* xbf      = (short*)(wsb + 131072);       // 2048x1024
  short* a_buf    = (short*)(wsb + 8519680);      // 6272x1024
  short* as_buf   = (short*)(wsb + 21364736);     // 2048x2048
  short* yexp     = (short*)(wsb + 29753344);     // 6272x1024
  short* wbf_sfc1 = (short*)(wsb + 42598400);     // 4096x1024
  short* wbf_sfc2 = (short*)(wsb + 50987008);     // 1024x2048
  short* wbf_fc1  = (short*)(wsb + 55181312);     // 15x2048x1024
  short* wbf_fc2  = (short*)(wsb + 118095872);    // 15x1024x1024
  // total ~149.6 MB

  k_convert_w<<<6528, 256, 0, stream>>>(fc1_w, fc2_w, s_fc1_w, s_fc2_w,
                                        wbf_fc1, wbf_fc2, wbf_sfc1, wbf_sfc2);
  k_gate<<<512, 64, 0, stream>>>(x, gate_w, topk_idx, topk_w, xbf);
  k_route<<<1, 1024, 0, stream>>>(topk_idx, topk_w, cnt, offs, row_tok, row_wt, row_id);
  // fc1: 128 shared + 39 max expert ty-tiles x 8 f = 440 blocks
  k_fc1<<<440, 512, 0, stream>>>(xbf, wbf_sfc1, s_fc1_b, s_mult,
                                 wbf_fc1, fc1_b, geglu_mult,
                                 cnt, offs, row_tok, as_buf, a_buf);
  // fc2: 64 shared + 39 x 8 = 376 blocks
  k_fc2<<<376, 512, 0, stream>>>(as_buf, wbf_sfc2, s_fc2_b,
                                 a_buf, wbf_fc2, fc2_b,
                                 cnt, offs, row_wt, y, yexp);
  k_combine<<<2048, 256, 0, stream>>>(y, yexp, row_id);
}

// Round 7
// 411.533 us; speedup vs baseline: 1.0979x; 1.0104x over previous
//
#include <hip/hip_runtime.h>

typedef __attribute__((ext_vector_type(8))) short bfrag;
typedef __attribute__((ext_vector_type(4))) float f32x4;

__device__ __forceinline__ short f2bf(float f) {
  union { float f; unsigned u; } v; v.f = f;
  unsigned r = v.u + 0x7FFFu + ((v.u >> 16) & 1u);  // RNE
  return (short)(r >> 16);
}
__device__ __forceinline__ float bf2f(unsigned short h) {
  union { unsigned u; float f; } v; v.u = ((unsigned)h) << 16;
  return v.f;
}
__device__ __forceinline__ float gelu_exact(float g) {
  return 0.5f * g * (1.0f + erff(g * 0.70710678118654752f));
}
__device__ __forceinline__ void gld_lds16(const short* g, short* l) {
  __builtin_amdgcn_global_load_lds(
      (const __attribute__((address_space(1))) void*)g,
      (__attribute__((address_space(3))) void*)l, 16, 0, 0);
}

// ---------------- weights -> bf16 ----------------
// 8 float4/thread, ALL loads issued before any store; NT loads on read-once fp32.
__global__ __launch_bounds__(256) void k_convert_w(
    const float* __restrict__ s0, const float* __restrict__ s1,
    const float* __restrict__ s2, const float* __restrict__ s3,
    short* __restrict__ d0, short* __restrict__ d1,
    short* __restrict__ d2, short* __restrict__ d3)
{
  const int b = blockIdx.x;
  const float* s; short* d; long off;
  if (b < 3840)      { s = s0; d = d0; off = (long)b * 2048; }
  else if (b < 5760) { s = s1; d = d1; off = (long)(b - 3840) * 2048; }
  else if (b < 6272) { s = s2; d = d2; off = (long)(b - 5760) * 2048; }
  else               { s = s3; d = d3; off = (long)(b - 6272) * 2048; }
  const f32x4* sp = (const f32x4*)s;
  const long i0 = off + threadIdx.x;
  f32x4 v[8];
#pragma unroll
  for (int j = 0; j < 8; j++) v[j] = __builtin_nontemporal_load(sp + i0 + j * 256);
#pragma unroll
  for (int j = 0; j < 8; j++)
    ((short4*)d)[i0 + j * 256] =
        make_short4(f2bf(v[j].x), f2bf(v[j].y), f2bf(v[j].z), f2bf(v[j].w));
}

// ---------------- gating (4 tokens/wave) + x->bf16 fused ----------------
__global__ __launch_bounds__(64) void k_gate(const float* __restrict__ x,
    const float* __restrict__ gw, int* __restrict__ topk_idx,
    float* __restrict__ topk_w, short* __restrict__ xbf)
{
  const int t0 = blockIdx.x * 4;
  const int lane = threadIdx.x;
  float xv[4][16];
#pragma unroll
  for (int tt = 0; tt < 4; tt++)
#pragma unroll
    for (int i = 0; i < 16; i++) {
      xv[tt][i] = x[(size_t)(t0 + tt) * 1024 + lane + 64 * i];
      xbf[(size_t)(t0 + tt) * 1024 + lane + 64 * i] = f2bf(xv[tt][i]);
    }
  float p[4][15];
#pragma unroll
  for (int e = 0; e < 15; e++) {
    float wv[16];
#pragma unroll
    for (int i = 0; i < 16; i++) wv[i] = gw[(size_t)e * 1024 + lane + 64 * i];
#pragma unroll
    for (int tt = 0; tt < 4; tt++) {
      float s = 0.f;
#pragma unroll
      for (int i = 0; i < 16; i++) s += xv[tt][i] * wv[i];
#pragma unroll
      for (int o = 32; o; o >>= 1) s += __shfl_xor(s, o, 64);
      p[tt][e] = s;
    }
  }
#pragma unroll
  for (int tt = 0; tt < 4; tt++) {
    float m = -1e30f;
#pragma unroll
    for (int e = 0; e < 15; e++) m = fmaxf(m, p[tt][e]);
    float q[15], Z = 0.f;
#pragma unroll
    for (int e = 0; e < 15; e++) { q[e] = expf(p[tt][e] - m); Z += q[e]; }
    int usedMask = 0; int bi[3]; float bv[3];
#pragma unroll
    for (int j = 0; j < 3; j++) {
      float best = -1.f; int b = 0;
#pragma unroll
      for (int e = 0; e < 15; e++) {
        bool ok = (!((usedMask >> e) & 1)) && (q[e] > best);
        if (ok) { best = q[e]; b = e; }
      }
      bi[j] = b; bv[j] = best / Z; usedMask |= 1 << b;
    }
    if (lane == tt) {
      float den = bv[0] + bv[1] + bv[2] + 1e-20f;
#pragma unroll
      for (int j = 0; j < 3; j++) {
        topk_idx[(t0 + tt) * 3 + j] = bi[j];
        topk_w[(t0 + tt) * 3 + j] = bv[j] / den;
      }
    }
  }
}

// ---------------- routing: single block, LDS atomics ----------------
__global__ __launch_bounds__(1024) void k_route(const int* __restrict__ topk_idx,
    const float* __restrict__ topk_w, int* __restrict__ cnt_g, int* __restrict__ offs_g,
    int* __restrict__ row_tok, float* __restrict__ row_wt, int* __restrict__ row_id)
{
  __shared__ int scnt[16], soffs[16], sfill[16];
  const int tid = threadIdx.x;
  if (tid < 16) { scnt[tid] = 0; sfill[tid] = 0; }
  __syncthreads();
  for (int i = tid; i < 6144; i += 1024) atomicAdd(&scnt[topk_idx[i]], 1);
  __syncthreads();
  if (tid == 0) {
    int a = 0;
    for (int e = 0; e < 15; e++) { soffs[e] = a; offs_g[e] = a; cnt_g[e] = scnt[e]; a += scnt[e]; }
  }
  __syncthreads();
  for (int i = tid; i < 6144; i += 1024) {
    int e = topk_idx[i];
    int pos = atomicAdd(&sfill[e], 1);
    int row = soffs[e] + pos;
    row_tok[row] = i / 3;
    row_wt[row] = topk_w[i];
    row_id[i] = row;
  }
}

__device__ __forceinline__ bool resolve_tile256(const int* __restrict__ cnt, int ty,
                                                int& e, int& lt) {
  int acc = 0;
#pragma unroll
  for (int i = 0; i < 15; i++) {
    int tl = (cnt[i] + 255) >> 8;
    if (ty < acc + tl) { e = i; lt = ty - acc; return true; }
    acc += tl;
  }
  return false;
}

// ============== unified fc1 (+geglu): shared blocks [0,128), expert [128,512) ==============
// 256(M) x 128(F) tile, 8 waves. XCD-locality block remap: all blocks sharing an
// A-panel (same m-tile / same (e,ty)) have bid = const (mod 8) -> same XCD ->
// A staged from that XCD's L2 after first touch (staging measured src-BW-bound
// at 4.3 TB/s across 3 schedules; m97 evidence gld_lds sustains 14 TB/s L2-src).
//   shared: bid = f*8 + m   (m-tiles 8, f-tiles 16)
//   expert: b2 = f*48 + ty  (ty slots 48 >= worst-case 39, 48%8==0)
__global__ __launch_bounds__(512, 2) void k_fc1(
    const short* __restrict__ xbf,
    const short* __restrict__ wsh, const float* __restrict__ bsh, const float* __restrict__ msh,
    const short* __restrict__ wex, const float* __restrict__ bex, const float* __restrict__ mex,
    const int* __restrict__ cnt, const int* __restrict__ offs, const int* __restrict__ row_tok,
    short* __restrict__ as_buf, short* __restrict__ a_buf)
{
  __shared__ short smem[2 * 32768];  // 128 KB: 2 x {A 32KB, B 32KB}
  const int tid = threadIdx.x;
  const int bid = blockIdx.x;
  const bool sh = bid < 128;
  int f0, m0 = 0, e = 0, rowBase = 0, nrows = 256;
  if (sh) {
    f0 = (bid >> 3) * 128; m0 = (bid & 7) * 256;   // XCD = m%8
  } else {
    const int b2 = bid - 128;
    const int f = b2 / 48;                          // 0..7
    const int ty = b2 % 48;                         // XCD = ty%8
    int lt;
    if (!resolve_tile256(cnt, ty, e, lt)) return;
    f0 = f * 128;
    rowBase = offs[e] + lt * 256;
    nrows = cnt[e] - lt * 256; if (nrows > 256) nrows = 256;
  }
  const int lane = tid & 63, ml = lane & 15, kq = lane >> 4, mlo = lane & 7;
  const int wv = tid >> 6, wr = wv >> 2, wc = wv & 3;
  const int lrow = lane >> 3, lchk = lane & 7;
  const int Fhalf = sh ? 2048 : 1024;
  const short* wptr = sh ? wsh : (wex + (size_t)e * 2048 * 1024);
  const short* aSrc[4]; const short* bSrc[4];
#pragma unroll
  for (int t = 0; t < 4; t++) {
    const int r = wv * 32 + t * 8 + lrow;          // 0..255
    const int sc = (lchk ^ (r & 7)) * 8;
    if (sh) aSrc[t] = xbf + (size_t)(m0 + r) * 1024 + sc;
    else {
      const int rc = r < nrows ? r : nrows - 1;
      aSrc[t] = xbf + (size_t)row_tok[rowBase + rc] * 1024 + sc;
    }
    const int grow = (r < 128) ? (f0 + r) : (Fhalf + f0 + r - 128);
    bSrc[t] = wptr + (size_t)grow * 1024 + sc;
  }
  f32x4 acc[8][4] = {};

#define FC1_STAGE(BUF, K0) do {                                              \
    short* A_ = smem + (BUF) * 32768;                                        \
    short* B_ = A_ + 16384;                                                  \
    _Pragma("unroll")                                                        \
    for (int t = 0; t < 4; t++) gld_lds16(aSrc[t] + (K0), A_ + (wv * 32 + t * 8) * 64); \
    _Pragma("unroll")                                                        \
    for (int t = 0; t < 4; t++) gld_lds16(bSrc[t] + (K0), B_ + (wv * 32 + t * 8) * 64); \
  } while (0)

#define FC1_COMPUTE(BUF) do {                                                \
    const short* As_ = smem + (BUF) * 32768;                                 \
    const short* Bs_ = As_ + 16384;                                          \
    _Pragma("unroll")                                                        \
    for (int kk = 0; kk < 2; kk++) {                                         \
      const int so = ((kk * 4 + kq) ^ mlo) * 8;                              \
      bfrag af[8], bb[4];                                                    \
      _Pragma("unroll")                                                      \
      for (int i = 0; i < 8; i++)                                            \
        af[i] = *(const bfrag*)&As_[(wr * 128 + i * 16 + ml) * 64 + so];     \
      _Pragma("unroll")                                                      \
      for (int j = 0; j < 4; j++) {                                          \
        const int brow = (j >> 1) * 128 + wc * 32 + (j & 1) * 16 + ml;       \
        bb[j] = *(const bfrag*)&Bs_[brow * 64 + so];                         \
      }                                                                      \
      _Pragma("unroll")                                                      \
      for (int i = 0; i < 8; i++)                                            \
        _Pragma("unroll")                                                    \
        for (int j = 0; j < 4; j++)                                          \
          acc[i][j] = __builtin_amdgcn_mfma_f32_16x16x32_bf16(af[i], bb[j], acc[i][j], 0, 0, 0); \
    }                                                                        \
  } while (0)

  FC1_STAGE(0, 0);
  __syncthreads();
  int cur = 0;
  for (int ks = 0; ks < 15; ks++) {
    FC1_STAGE(cur ^ 1, (ks + 1) * 64);  // prefetch next tile (overlaps compute)
    FC1_COMPUTE(cur);
    __syncthreads();                     // drains vmcnt: next buffer ready
    cur ^= 1;
  }
  FC1_COMPUTE(cur);

  // in-register geglu epilogue: 64 outputs/lane
  const float* bias = sh ? bsh : (bex + (size_t)e * 2048);
  const float* mult = sh ? msh : (mex + (size_t)e * 1024);
#pragma unroll
  for (int jj = 0; jj < 2; jj++) {
    const int fl = wc * 32 + jj * 16 + ml;
    const int f = f0 + fl;
    const float b1 = bias[f];
    const float b2 = bias[Fhalf + f];
    const float mv = mult[f];
#pragma unroll
    for (int i = 0; i < 8; i++)
#pragma unroll
      for (int rg = 0; rg < 4; rg++) {
        const int row = wr * 128 + i * 16 + kq * 4 + rg;
        const float h1 = acc[i][jj][rg] + b1;
        const float h2 = acc[i][jj + 2][rg] + b2;
        const short o = f2bf(gelu_exact(h2) * h1 * mv);
        if (sh) as_buf[(size_t)(m0 + row) * 2048 + f] = o;
        else if (row < nrows) a_buf[(size_t)(rowBase + row) * 1024 + f] = o;
      }
  }
}

// ============== unified fc2: shared blocks [0,64), expert [64,448) ==============
// 256(M) x 128(D) tile, 8 waves; same XCD-locality remap:
//   shared: bid = d*8 + m   (m-tiles 8, d-tiles 8)
//   expert: b2 = d*48 + ty
__global__ __launch_bounds__(512, 2) void k_fc2(
    const short* __restrict__ as_buf, const short* __restrict__ wsfc2, const float* __restrict__ s_b,
    const short* __restrict__ a_buf, const short* __restrict__ wfc2, const float* __restrict__ e_b,
    const int* __restrict__ cnt, const int* __restrict__ offs, const float* __restrict__ row_wt,
    float* __restrict__ y, short* __restrict__ yexp)
{
  __shared__ short smem[2 * 24576];  // 96 KB: 2 x {A 32KB, B 16KB}
  const int tid = threadIdx.x;
  const int bid = blockIdx.x;
  const bool sh = bid < 64;
  int d0, m0 = 0, e = 0, rowBase = 0, nrows = 256, Klen, astr, bstr;
  const short *aBase, *bBase;
  if (sh) {
    d0 = (bid >> 3) * 128; m0 = (bid & 7) * 256;   // XCD = m%8
    Klen = 2048; astr = 2048; bstr = 2048;
    aBase = as_buf; bBase = wsfc2;
  } else {
    const int b2 = bid - 64;
    const int dq = b2 / 48;                         // 0..7
    const int ty = b2 % 48;                         // XCD = ty%8
    int lt;
    if (!resolve_tile256(cnt, ty, e, lt)) return;
    d0 = dq * 128;
    rowBase = offs[e] + lt * 256;
    nrows = cnt[e] - lt * 256; if (nrows > 256) nrows = 256;
    Klen = 1024; astr = 1024; bstr = 1024;
    aBase = a_buf + (size_t)rowBase * 1024;
    bBase = wfc2 + (size_t)e * 1024 * 1024;
  }
  const int lane = tid & 63, ml = lane & 15, kq = lane >> 4, mlo = lane & 7;
  const int wv = tid >> 6, wr = wv >> 2, wc = wv & 3;
  const int lrow = lane >> 3, lchk = lane & 7;
  const short* aSrc[4]; const short* bSrc[2];
#pragma unroll
  for (int t = 0; t < 4; t++) {
    const int r = wv * 32 + t * 8 + lrow;          // 0..255
    const int sc = (lchk ^ (r & 7)) * 8;
    const int rc = (sh || r < nrows) ? r : nrows - 1;
    aSrc[t] = aBase + (size_t)(sh ? (m0 + r) : rc) * astr + sc;
  }
#pragma unroll
  for (int t = 0; t < 2; t++) {
    const int rb = wv * 16 + t * 8 + lrow;         // 0..127
    const int sc = (lchk ^ (rb & 7)) * 8;
    bSrc[t] = bBase + (size_t)(d0 + rb) * bstr + sc;
  }
  f32x4 acc[8][2] = {};

#define FC2_STAGE(BUF, K0) do {                                              \
    short* A_ = smem + (BUF) * 24576;                                        \
    short* B_ = A_ + 16384;                                                  \
    _Pragma("unroll")                                                        \
    for (int t = 0; t < 4; t++) gld_lds16(aSrc[t] + (K0), A_ + (wv * 32 + t * 8) * 64); \
    _Pragma("unroll")                                                        \
    for (int t = 0; t < 2; t++) gld_lds16(bSrc[t] + (K0), B_ + (wv * 16 + t * 8) * 64); \
  } while (0)

#define FC2_COMPUTE(BUF) do {                                                \
    const short* As_ = smem + (BUF) * 24576;                                 \
    const short* Bs_ = As_ + 16384;                                          \
    _Pragma("unroll")                                                        \
    for (int kk = 0; kk < 2; kk++) {                                         \
      const int so = ((kk * 4 + kq) ^ mlo) * 8;                              \
      bfrag af[8], bb[2];                                                    \
      _Pragma("unroll")                                                      \
      for (int i = 0; i < 8; i++)                                            \
        af[i] = *(const bfrag*)&As_[(wr * 128 + i * 16 + ml) * 64 + so];     \
      _Pragma("unroll")                                                      \
      for (int j = 0; j < 2; j++)                                            \
        bb[j] = *(const bfrag*)&Bs_[(wc * 32 + j * 16 + ml) * 64 + so];      \
      _Pragma("unroll")                                                      \
      for (int i = 0; i < 8; i++)                                            \
        _Pragma("unroll")                                                    \
        for (int j = 0; j < 2; j++)                                          \
          acc[i][j] = __builtin_amdgcn_mfma_f32_16x16x32_bf16(af[i], bb[j], acc[i][j], 0, 0, 0); \
    }                                                                        \
  } while (0)

  FC2_STAGE(0, 0);
  __syncthreads();
  int cur = 0;
  const int NK = Klen >> 6;
  for (int ks = 0; ks < NK - 1; ks++) {
    FC2_STAGE(cur ^ 1, (ks + 1) * 64);
    FC2_COMPUTE(cur);
    __syncthreads();
    cur ^= 1;
  }
  FC2_COMPUTE(cur);

#pragma unroll
  for (int j = 0; j < 2; j++) {
    const int d = d0 + wc * 32 + j * 16 + ml;
    const float bv = sh ? s_b[d] : e_b[(size_t)e * 1024 + d];
#pragma unroll
    for (int i = 0; i < 8; i++)
#pragma unroll
      for (int rg = 0; rg < 4; rg++) {
        const int row = wr * 128 + i * 16 + kq * 4 + rg;
        if (sh) {
          y[(size_t)(m0 + row) * 1024 + d] = acc[i][j][rg] + bv;
        } else if (row < nrows) {
          const float wt = row_wt[rowBase + row];
          yexp[(size_t)(rowBase + row) * 1024 + d] = f2bf((acc[i][j][rg] + bv) * wt);
        }
      }
  }
}

// ---------------- combine ----------------
__global__ __launch_bounds__(256) void k_combine(float* __restrict__ y,
    const short* __restrict__ yexp, const int* __restrict__ row_id)
{
  const int idx = blockIdx.x * 256 + threadIdx.x;
  const int t = idx >> 8;
  const int d4 = (idx & 255) * 4;
  const int r0 = row_id[t * 3], r1 = row_id[t * 3 + 1], r2 = row_id[t * 3 + 2];
  float4 acc = *(float4*)(y + (size_t)t * 1024 + d4);
  const ushort4 v0 = *(const ushort4*)(yexp + (size_t)r0 * 1024 + d4);
  const ushort4 v1 = *(const ushort4*)(yexp + (size_t)r1 * 1024 + d4);
  const ushort4 v2 = *(const ushort4*)(yexp + (size_t)r2 * 1024 + d4);
  acc.x += bf2f(v0.x) + bf2f(v1.x) + bf2f(v2.x);
  acc.y += bf2f(v0.y) + bf2f(v1.y) + bf2f(v2.y);
  acc.z += bf2f(v0.z) + bf2f(v1.z) + bf2f(v2.z);
  acc.w += bf2f(v0.w) + bf2f(v1.w) + bf2f(v2.w);
  *(float4*)(y + (size_t)t * 1024 + d4) = acc;
}

extern "C" void kernel_launch(void* const* d_in, const int* in_sizes, int n_in,
                              void* d_out, int out_size, void* d_ws, size_t ws_size,
                              hipStream_t stream) {
  const float* x          = (const float*)d_in[0];
  const float* gate_w     = (const float*)d_in[1];
  const float* fc1_w      = (const float*)d_in[2];
  const float* fc1_b      = (const float*)d_in[3];
  const float* geglu_mult = (const float*)d_in[4];
  const float* fc2_w      = (const float*)d_in[5];
  const float* fc2_b      = (const float*)d_in[6];
  const float* s_fc1_w    = (const float*)d_in[7];
  const float* s_fc1_b    = (const float*)d_in[8];
  const float* s_mult     = (const float*)d_in[9];
  const float* s_fc2_w    = (const float*)d_in[10];
  const float* s_fc2_b    = (const float*)d_in[11];
  float* y = (float*)d_out;

  char* wsb = (char*)d_ws;
  int*   cnt      = (int*)(wsb + 0);
  int*   offs     = (int*)(wsb + 64);
  int*   topk_idx = (int*)(wsb + 256);
  float* topk_w   = (float*)(wsb + 24832);
  int*   row_tok  = (int*)(wsb + 49408);
  float* row_wt   = (float*)(wsb + 74496);
  int*   row_id   = (int*)(wsb + 99584);
  short* xbf      = (short*)(wsb + 131072);       // 2048x1024
  short* a_buf    = (short*)(wsb + 8519680);      // 6272x1024
  short* as_buf   = (short*)(wsb + 21364736);     // 2048x2048
  short* yexp     = (short*)(wsb + 29753344);     // 6272x1024
  short* wbf_sfc1 = (short*)(wsb + 42598400);     // 4096x1024
  short* wbf_sfc2 = (short*)(wsb + 50987008);     // 1024x2048
  short* wbf_fc1  = (short*)(wsb + 55181312);     // 15x2048x1024
  short* wbf_fc2  = (short*)(wsb + 118095872);    // 15x1024x1024
  // total ~149.6 MB

  k_convert_w<<<6528, 256, 0, stream>>>(fc1_w, fc2_w, s_fc1_w, s_fc2_w,
                                        wbf_fc1, wbf_fc2, wbf_sfc1, wbf_sfc2);
  k_gate<<<512, 64, 0, stream>>>(x, gate_w, topk_idx, topk_w, xbf);
  k_route<<<1, 1024, 0, stream>>>(topk_idx, topk_w, cnt, offs, row_tok, row_wt, row_id);
  // fc1: 128 shared + 8 f x 48 ty slots = 512 blocks (dead ty slots exit early)
  k_fc1<<<512, 512, 0, stream>>>(xbf, wbf_sfc1, s_fc1_b, s_mult,
                                 wbf_fc1, fc1_b, geglu_mult,
                                 cnt, offs, row_tok, as_buf, a_buf);
  // fc2: 64 shared + 8 d x 48 ty slots = 448 blocks
  k_fc2<<<448, 512, 0, stream>>>(as_buf, wbf_sfc2, s_fc2_b,
                                 a_buf, wbf_fc2, fc2_b,
                                 cnt, offs, row_wt, y, yexp);
  k_combine<<<2048, 256, 0, stream>>>(y, yexp, row_id);
}